// Round 5
// baseline (5371.052 us; speedup 1.0000x reference)
//
#include <hip/hip_runtime.h>

// GraphSAGE-CF on MI355X — round 10.
// Rounds 6/7/9 all spilled at VGPR caps 72-85: the flush-based gather's true
// live state is ~98 regs (cs/ce/rr/nend/gacc/ec x8 + acc2 + temps). Rounds
// 5/8 (cap 128) never spill but occupancy pins at ~0.8x(bound/8) -> 40%.
// Fix the deadlock by shrinking the gather itself:
//   * fill_kernel packs dest row INTO the edge: x = col(18b) | P(12b)<<18,
//     P = (rowlocal<<6)|xsw -> swizzled LDS word = ((x>>18)&0xFFF) ^ lane.
//   * gather becomes stateless streaming: per edge = 1 uniform edge load,
//     1 coalesced row load, v_mul, ds_add_f32. No row tracking, no binary
//     search, no flush logic, no rp_s. Peak regs ~66 (ec/en prefetch 32 +
//     acc2 16 + temps) -> fits cap 84.
// Keep round-9 quarter-staged Ws (8KB) + Xs 16KB = LDS 24576 -> 6 blocks/CU
// at launch_bounds(256,6) (occupancy ~61% per rounds 7/9 evidence).
//
// ws layout (4-byte words):
//   WuT[2][128][64] @0   WiT @16384          Wt[l][k][j]=W[l][j][k]
//   hu1[200000][64]                          layer-0 user out
//   hi1[100000][64]                          layer-0 item out
//   edges_u uint2[3.2M]   (col|P<<18, w bits) by user row
//   edges_i uint2[3.2M]   (col|P<<18, w bits) by item row
//   rank_u ushort[3.2M]  rank_i ushort[3.2M]
//   rowptr_u[200001]  rowptr_i[100001]
//   deg_u[200000]  deg_i[100000]
//   bsum_u[782] bpre_u[782] bsum_i[391] bpre_i[391]

#define N_USERS 200000
#define N_ITEMS 100000
#define N_EDGES 3200000
#define NB_U 782      // ceil(200000/256)
#define NB_I 391      // ceil(100000/256)

typedef float v2f __attribute__((ext_vector_type(2)));

// ---------- W convert + transpose:  Wt[l][k][j] = W[l][j][k] ----------
__global__ __launch_bounds__(256) void wprep_kernel(
    const float* __restrict__ Wu, const float* __restrict__ Wi,
    float* __restrict__ WuT, float* __restrict__ WiT)
{
    int idx = blockIdx.x * 256 + threadIdx.x;     // 0..32767
    const float* src = Wu;
    float* dst = WuT;
    int i = idx;
    if (idx >= 16384) { src = Wi; dst = WiT; i = idx - 16384; }
    int l = i >> 13;
    int r = i & 8191;
    int j = r >> 7;           // out col 0..63
    int k = r & 127;          // in  idx 0..127
    dst[l * 8192 + k * 64 + j] = src[i];
}

// ---------- degree histogram + per-edge rank (atomic return is the rank) ----
__global__ __launch_bounds__(256) void hist_kernel(
    const int* __restrict__ u_idx, const int* __restrict__ i_idx,
    int* __restrict__ deg_u, int* __restrict__ deg_i,
    unsigned short* __restrict__ rank_u, unsigned short* __restrict__ rank_i)
{
    int t = blockIdx.x * 256 + threadIdx.x;     // < 2E
    if (t < N_EDGES) {
        rank_u[t] = (unsigned short)atomicAdd(&deg_u[u_idx[t]], 1);
    } else {
        int e = t - N_EDGES;
        rank_i[e] = (unsigned short)atomicAdd(&deg_i[i_idx[e]], 1);
    }
}

// ---------- scan phase A: per-block sums ----------
__global__ __launch_bounds__(256) void scanA_kernel(
    const int* __restrict__ deg_u, const int* __restrict__ deg_i,
    int* __restrict__ bsum_u, int* __restrict__ bsum_i)
{
    int b = blockIdx.x;
    const int* deg; int n; int* bs; int bb;
    if (b < NB_U) { deg = deg_u; n = N_USERS; bs = bsum_u; bb = b; }
    else          { deg = deg_i; n = N_ITEMS; bs = bsum_i; bb = b - NB_U; }
    int i = bb * 256 + threadIdx.x;
    int v = (i < n) ? deg[i] : 0;
    #pragma unroll
    for (int off = 1; off < 64; off <<= 1) v += __shfl_xor(v, off);
    __shared__ int ws4[4];
    int wv = threadIdx.x >> 6;
    if ((threadIdx.x & 63) == 0) ws4[wv] = v;
    __syncthreads();
    if (threadIdx.x == 0) bs[bb] = ws4[0] + ws4[1] + ws4[2] + ws4[3];
}

// ---------- scan phase B: exclusive scan of block sums ----------
__global__ __launch_bounds__(1024) void scanB_kernel(
    const int* __restrict__ bsum_u, int* __restrict__ bpre_u,
    const int* __restrict__ bsum_i, int* __restrict__ bpre_i)
{
    __shared__ int s[1024];
    const int* src; int* dst; int n;
    if (blockIdx.x == 0) { src = bsum_u; dst = bpre_u; n = NB_U; }
    else                 { src = bsum_i; dst = bpre_i; n = NB_I; }
    int t = threadIdx.x;
    int v = (t < n) ? src[t] : 0;
    s[t] = v; __syncthreads();
    #pragma unroll
    for (int off = 1; off < 1024; off <<= 1) {
        int x = (t >= off) ? s[t - off] : 0;
        __syncthreads();
        s[t] += x;
        __syncthreads();
    }
    if (t < n) dst[t] = s[t] - v;   // exclusive
}

// ---------- scan phase C: rowptr = bpre + intra-block exclusive ----------
__global__ __launch_bounds__(256) void scanC_kernel(
    const int* __restrict__ deg_u, const int* __restrict__ deg_i,
    const int* __restrict__ bpre_u, const int* __restrict__ bpre_i,
    int* __restrict__ rowptr_u, int* __restrict__ rowptr_i)
{
    int b = blockIdx.x;
    const int* deg; int n; const int* bpre; int* rowptr; int bb;
    if (b < NB_U) { deg = deg_u; n = N_USERS; bpre = bpre_u; rowptr = rowptr_u; bb = b; }
    else          { deg = deg_i; n = N_ITEMS; bpre = bpre_i; rowptr = rowptr_i; bb = b - NB_U; }
    int t = threadIdx.x;
    int i = bb * 256 + t;
    int d = (i < n) ? deg[i] : 0;
    __shared__ int s[256];
    s[t] = d; __syncthreads();
    #pragma unroll
    for (int off = 1; off < 256; off <<= 1) {
        int x = (t >= off) ? s[t - off] : 0;
        __syncthreads();
        s[t] += x;
        __syncthreads();
    }
    int val = bpre[bb] + (s[t] - d);
    if (i < n) rowptr[i] = val;
    if (b == 0 && t == 0) { rowptr_u[N_USERS] = N_EDGES; rowptr_i[N_ITEMS] = N_EDGES; }
}

// ---------- CSR fill: no atomics; XCD-partitioned by destination row ----------
// Packs dest-row info into edge.x: bits 0..17 = col, bits 18..29 =
// P = (rowlocal<<6) | xsw, where xsw = ((rowlocal>>1)&3)<<3.
// Gather's LDS word index = ((x>>18)&0xFFF) ^ lane  (lane<64, xsw in low 6).
__global__ __launch_bounds__(256) void fill_kernel(
    const int* __restrict__ u_idx, const int* __restrict__ i_idx,
    const float* __restrict__ w_u2i, const float* __restrict__ w_i2u,
    const unsigned short* __restrict__ rank_u, const unsigned short* __restrict__ rank_i,
    const int* __restrict__ rowptr_u, const int* __restrict__ rowptr_i,
    uint2* __restrict__ edges_u, uint2* __restrict__ edges_i)
{
    const int part   = blockIdx.x & 7;
    const int slot   = blockIdx.x >> 3;
    const int nslots = gridDim.x >> 3;
    const int stride = nslots * 256;

    for (int e = slot * 256 + threadIdx.x; e < N_EDGES; e += stride) {
        int ru = u_idx[e];
        int ri = i_idx[e];
        if ((ru & 7) == part) {
            int p = rowptr_u[ru] + rank_u[e];
            unsigned rl = (unsigned)(ru & 63);
            unsigned P  = (rl << 6) | (((rl >> 1) & 3) << 3);
            edges_u[p] = make_uint2((unsigned)ri | (P << 18), __float_as_uint(w_u2i[e]));
        }
        if ((ri & 7) == part) {
            int p = rowptr_i[ri] + rank_i[e];
            unsigned rl = (unsigned)(ri & 63);
            unsigned P  = (rl << 6) | (((rl >> 1) & 3) << 3);
            edges_i[p] = make_uint2((unsigned)ru | (P << 18), __float_as_uint(w_i2u[e]));
        }
    }
}

// Xs column swizzle: word (row<<6) | (col ^ XSW(row)); XSW multiple of 8 so
// GEMM column reads spread over 4 banks (2-way aliased = free) and gather
// ds_adds stay a per-row lane permutation (conflict-free).
#define XSW(rr) ((((rr) >> 1) & 3) << 3)

// ---------- fused gather + dense transform + relu + l2norm (both sides) ----------
// LDS = Ws[2048] + Xs[4096] floats = 24576 B -> 6 blocks/CU at bounds(256,6).
// W staged in 8KB quarters (32 k-rows); 4 GEMM sub-phases.
// Gather: stateless streaming over the wave's edge sub-range, 8-edge batches
// with one-batch prefetch; dest LDS word precomputed in the edge record.
__global__ __launch_bounds__(256, 6) void transform_fused_kernel(
    const float* __restrict__ hself_u, const float* __restrict__ hsrc_u,
    const int* __restrict__ rowptr_u, const uint2* __restrict__ edges_u,
    const float* __restrict__ WtU, float* __restrict__ out_u,
    const float* __restrict__ hself_i, const float* __restrict__ hsrc_i,
    const int* __restrict__ rowptr_i, const uint2* __restrict__ edges_i,
    const float* __restrict__ WtI, float* __restrict__ out_i,
    int nbu)
{
    __shared__ float Ws[32 * 64];    // 8 KB
    __shared__ float Xs[64 * 64];    // 16 KB, XOR-swizzled columns

    const int tid = threadIdx.x;

    // ---- u,u,i interleave: spreads the heavy (2x gather) item blocks ----
    const int nbt = (int)gridDim.x;
    const int nbi = nbt - nbu;
    int bid = (int)blockIdx.x;
    int g = bid / 3, r = bid - 3 * g;
    bool is_u; int bb;
    if (r < 2) {
        int cand = 2 * g + r;
        if (cand < nbu) { is_u = true;  bb = cand; }
        else            { is_u = false; bb = nbi - (nbt - bid); }
    } else {
        int cand = g;
        if (cand < nbi) { is_u = false; bb = cand; }
        else            { is_u = true;  bb = nbu - (nbt - bid); }
    }

    const float* hself; const float* hsrc; const int* rowptr;
    const uint2* edges; const float* Wt; float* out; int N;
    if (is_u) {
        hself = hself_u; hsrc = hsrc_u; rowptr = rowptr_u; edges = edges_u;
        Wt = WtU; out = out_u; N = N_USERS;
    } else {
        hself = hself_i; hsrc = hsrc_i; rowptr = rowptr_i; edges = edges_i;
        Wt = WtI; out = out_i; N = N_ITEMS;
    }
    const int row0 = bb * 64;

    const int tr = tid >> 3;     // 0..31
    const int tc = tid & 7;      // 0..7
    const int r0 = 2 * tr;
    const int xsw = XSW(r0);     // same for rows r0 and r0+1

    v2f acc2[2][4];
    #pragma unroll
    for (int j = 0; j < 2; ++j)
        #pragma unroll
        for (int c = 0; c < 4; ++c) acc2[j][c] = (v2f){0.f, 0.f};

    // ---- stage self tile into swizzled Xs + Ws quarter 0 (k=0..31) ----
    {
        const float4* wsrc = (const float4*)Wt;
        float4* wdst = (float4*)Ws;
        wdst[tid]       = wsrc[tid];
        wdst[tid + 256] = wsrc[tid + 256];
        #pragma unroll
        for (int i = 0; i < 4; ++i) {
            int idx4 = tid + i * 256;          // float4 index 0..1023
            int rr = idx4 >> 4, c4 = idx4 & 15;
            int gr = row0 + rr; if (gr > N - 1) gr = N - 1;
            float4 v = ((const float4*)(hself + (size_t)gr * 64))[c4];
            // (4*c4+j) ^ XSW = 4*(c4 ^ (XSW>>2)) + j  (XSW is a multiple of 8)
            ((float4*)Xs)[(rr << 4) + (c4 ^ (XSW(rr) >> 2))] = v;
        }
    }
    __syncthreads();

    // ---- GEMM A1: self features, dims 0..31 ----
    #pragma unroll 8
    for (int k2 = 0; k2 < 32; ++k2) {
        int kk = k2;
        float a0 = Xs[(r0 << 6) + (kk ^ xsw)];
        float a1 = Xs[((r0 + 1) << 6) + (kk ^ xsw)];
        float4 b0 = *(const float4*)&Ws[k2 * 64 + 8 * tc];
        float4 b1 = *(const float4*)&Ws[k2 * 64 + 8 * tc + 4];
        v2f bv0 = {b0.x, b0.y}, bv1 = {b0.z, b0.w};
        v2f bv2 = {b1.x, b1.y}, bv3 = {b1.z, b1.w};
        v2f a0v = {a0, a0}, a1v = {a1, a1};
        acc2[0][0] += a0v * bv0; acc2[0][1] += a0v * bv1;
        acc2[0][2] += a0v * bv2; acc2[0][3] += a0v * bv3;
        acc2[1][0] += a1v * bv0; acc2[1][1] += a1v * bv1;
        acc2[1][2] += a1v * bv2; acc2[1][3] += a1v * bv3;
    }
    __syncthreads();

    // ---- stage Ws quarter 1 (k=32..63) ----
    {
        const float4* wsrc = (const float4*)(Wt + 2048);
        float4* wdst = (float4*)Ws;
        wdst[tid]       = wsrc[tid];
        wdst[tid + 256] = wsrc[tid + 256];
    }
    __syncthreads();

    // ---- GEMM A2: self features, dims 32..63 ----
    #pragma unroll 8
    for (int k2 = 0; k2 < 32; ++k2) {
        int kk = 32 + k2;
        float a0 = Xs[(r0 << 6) + (kk ^ xsw)];
        float a1 = Xs[((r0 + 1) << 6) + (kk ^ xsw)];
        float4 b0 = *(const float4*)&Ws[k2 * 64 + 8 * tc];
        float4 b1 = *(const float4*)&Ws[k2 * 64 + 8 * tc + 4];
        v2f bv0 = {b0.x, b0.y}, bv1 = {b0.z, b0.w};
        v2f bv2 = {b1.x, b1.y}, bv3 = {b1.z, b1.w};
        v2f a0v = {a0, a0}, a1v = {a1, a1};
        acc2[0][0] += a0v * bv0; acc2[0][1] += a0v * bv1;
        acc2[0][2] += a0v * bv2; acc2[0][3] += a0v * bv3;
        acc2[1][0] += a1v * bv0; acc2[1][1] += a1v * bv1;
        acc2[1][2] += a1v * bv2; acc2[1][3] += a1v * bv3;
    }
    __syncthreads();   // Ws q1 and self Xs dead

    // ---- zero Xs ----
    {
        float4 z = make_float4(0.f, 0.f, 0.f, 0.f);
        #pragma unroll
        for (int i = 0; i < 4; ++i) ((float4*)Xs)[tid + i * 256] = z;
    }
    __syncthreads();

    // ---- stateless streaming gather: ds_add per edge, dest packed in edge ----
    {
        const int wv = tid >> 6;
        const int ln = tid & 63;
        const int e0 = rowptr[row0];
        const int e1 = rowptr[min(row0 + 64, N)];
        const int tot  = e1 - e0;
        const int perw = (tot + 3) >> 2;
        const int wsb  = e0 + wv * perw;
        const int web  = min(wsb + perw, e1);

        int p = wsb;
        const int cnt = web - wsb;
        const int nfull = (cnt > 0) ? (cnt >> 3) : 0;

        uint2 ec[8];
        if (nfull > 0) {
            #pragma unroll
            for (int s = 0; s < 8; ++s) ec[s] = edges[p + s];
        }
        for (int b = 0; b < nfull; ++b) {
            const int pn = p + 8;
            uint2 en[8];
            const bool more = (b + 1 < nfull);
            if (more) {
                #pragma unroll
                for (int s = 0; s < 8; ++s) en[s] = edges[pn + s];
            }
            float hv[8];
            #pragma unroll
            for (int s = 0; s < 8; ++s)
                hv[s] = hsrc[(size_t)(ec[s].x & 0x3FFFFu) * 64 + ln];
            #pragma unroll
            for (int s = 0; s < 8; ++s) {
                int la = (int)((ec[s].x >> 18) & 0xFFFu) ^ ln;
                atomicAdd(&Xs[la], __uint_as_float(ec[s].y) * hv[s]);
            }
            if (more) {
                #pragma unroll
                for (int s = 0; s < 8; ++s) ec[s] = en[s];
            }
            p = pn;
        }
        // tail (< 8 edges)
        for (int q = p; q < web; ++q) {
            uint2 e = edges[q];
            float hval = hsrc[(size_t)(e.x & 0x3FFFFu) * 64 + ln];
            int la = (int)((e.x >> 18) & 0xFFFu) ^ ln;
            atomicAdd(&Xs[la], __uint_as_float(e.y) * hval);
        }
    }
    __syncthreads();   // gather done

    // ---- stage Ws quarter 2 (k=64..95) ----
    {
        const float4* wsrc = (const float4*)(Wt + 4096);
        float4* wdst = (float4*)Ws;
        wdst[tid]       = wsrc[tid];
        wdst[tid + 256] = wsrc[tid + 256];
    }
    __syncthreads();

    // ---- GEMM B1: neighbor features, dims 0..31 ----
    #pragma unroll 8
    for (int k2 = 0; k2 < 32; ++k2) {
        int kk = k2;
        float a0 = Xs[(r0 << 6) + (kk ^ xsw)];
        float a1 = Xs[((r0 + 1) << 6) + (kk ^ xsw)];
        float4 b0 = *(const float4*)&Ws[k2 * 64 + 8 * tc];
        float4 b1 = *(const float4*)&Ws[k2 * 64 + 8 * tc + 4];
        v2f bv0 = {b0.x, b0.y}, bv1 = {b0.z, b0.w};
        v2f bv2 = {b1.x, b1.y}, bv3 = {b1.z, b1.w};
        v2f a0v = {a0, a0}, a1v = {a1, a1};
        acc2[0][0] += a0v * bv0; acc2[0][1] += a0v * bv1;
        acc2[0][2] += a0v * bv2; acc2[0][3] += a0v * bv3;
        acc2[1][0] += a1v * bv0; acc2[1][1] += a1v * bv1;
        acc2[1][2] += a1v * bv2; acc2[1][3] += a1v * bv3;
    }
    __syncthreads();

    // ---- stage Ws quarter 3 (k=96..127) ----
    {
        const float4* wsrc = (const float4*)(Wt + 6144);
        float4* wdst = (float4*)Ws;
        wdst[tid]       = wsrc[tid];
        wdst[tid + 256] = wsrc[tid + 256];
    }
    __syncthreads();

    // ---- GEMM B2: neighbor features, dims 32..63 ----
    #pragma unroll 8
    for (int k2 = 0; k2 < 32; ++k2) {
        int kk = 32 + k2;
        float a0 = Xs[(r0 << 6) + (kk ^ xsw)];
        float a1 = Xs[((r0 + 1) << 6) + (kk ^ xsw)];
        float4 b0 = *(const float4*)&Ws[k2 * 64 + 8 * tc];
        float4 b1 = *(const float4*)&Ws[k2 * 64 + 8 * tc + 4];
        v2f bv0 = {b0.x, b0.y}, bv1 = {b0.z, b0.w};
        v2f bv2 = {b1.x, b1.y}, bv3 = {b1.z, b1.w};
        v2f a0v = {a0, a0}, a1v = {a1, a1};
        acc2[0][0] += a0v * bv0; acc2[0][1] += a0v * bv1;
        acc2[0][2] += a0v * bv2; acc2[0][3] += a0v * bv3;
        acc2[1][0] += a1v * bv0; acc2[1][1] += a1v * bv1;
        acc2[1][2] += a1v * bv2; acc2[1][3] += a1v * bv3;
    }

    // ---- epilogue: relu, row L2 norm (8 lanes per row), store ----
    #pragma unroll
    for (int j = 0; j < 2; ++j) {
        float v[8];
        v[0] = fmaxf(acc2[j][0].x, 0.f); v[1] = fmaxf(acc2[j][0].y, 0.f);
        v[2] = fmaxf(acc2[j][1].x, 0.f); v[3] = fmaxf(acc2[j][1].y, 0.f);
        v[4] = fmaxf(acc2[j][2].x, 0.f); v[5] = fmaxf(acc2[j][2].y, 0.f);
        v[6] = fmaxf(acc2[j][3].x, 0.f); v[7] = fmaxf(acc2[j][3].y, 0.f);
        float s = 0.f;
        #pragma unroll
        for (int c = 0; c < 8; ++c) s = fmaf(v[c], v[c], s);
        s += __shfl_xor(s, 1);
        s += __shfl_xor(s, 2);
        s += __shfl_xor(s, 4);
        float nrm = sqrtf(s);
        float inv = 1.f / fmaxf(nrm, 1e-12f);
        int gr = row0 + r0 + j;
        if (gr < N) {
            float4 o0 = make_float4(v[0]*inv, v[1]*inv, v[2]*inv, v[3]*inv);
            float4 o1 = make_float4(v[4]*inv, v[5]*inv, v[6]*inv, v[7]*inv);
            float* p = out + gr * 64 + 8 * tc;
            *(float4*)p       = o0;
            *(float4*)(p + 4) = o1;
        }
    }
}

extern "C" void kernel_launch(void* const* d_in, const int* in_sizes, int n_in,
                              void* d_out, int out_size, void* d_ws, size_t ws_size,
                              hipStream_t stream)
{
    (void)in_sizes; (void)n_in; (void)out_size; (void)ws_size;

    const float* user_emb = (const float*)d_in[0];
    const float* item_emb = (const float*)d_in[1];
    const float* Wu       = (const float*)d_in[2];
    const float* Wi       = (const float*)d_in[3];
    const int*   u_idx    = (const int*)d_in[4];
    const int*   i_idx    = (const int*)d_in[5];
    const float* w_u2i    = (const float*)d_in[6];
    const float* w_i2u    = (const float*)d_in[7];
    float* out = (float*)d_out;

    float* ws      = (float*)d_ws;
    float* WuT     = ws;                            // 16384
    float* WiT     = WuT + 16384;                   // 16384
    float* hu1     = WiT + 16384;                   // 12,800,000
    float* hi1     = hu1 + N_USERS * 64;            // 6,400,000
    uint2* edges_u = (uint2*)(hi1 + N_ITEMS * 64);  // 3.2M uint2
    uint2* edges_i = edges_u + N_EDGES;             // 3.2M uint2
    unsigned short* rank_u = (unsigned short*)(edges_i + N_EDGES);  // 3.2M ushort
    unsigned short* rank_i = rank_u + N_EDGES;                      // 3.2M ushort
    int* rowptr_u = (int*)(rank_i + N_EDGES);       // 200001
    int* rowptr_i = rowptr_u + (N_USERS + 1);       // 100001
    int* deg_u    = rowptr_i + (N_ITEMS + 1);       // 200000
    int* deg_i    = deg_u + N_USERS;                // 100000
    int* bsum_u   = deg_i + N_ITEMS;
    int* bpre_u   = bsum_u + NB_U;
    int* bsum_i   = bpre_u + NB_U;
    int* bpre_i   = bsum_i + NB_I;

    const int tu_blocks = (N_USERS + 63) / 64;        // 3125
    const int ti_blocks = (N_ITEMS + 63) / 64;        // 1563
    const int e2_blocks = (2 * N_EDGES) / 256;        // 25000

    // ---- CSR build (both sides) ----
    wprep_kernel<<<128, 256, 0, stream>>>(Wu, Wi, WuT, WiT);
    hipMemsetAsync(deg_u, 0, (size_t)(N_USERS + N_ITEMS) * 4, stream);
    hist_kernel<<<e2_blocks, 256, 0, stream>>>(u_idx, i_idx, deg_u, deg_i, rank_u, rank_i);
    scanA_kernel<<<NB_U + NB_I, 256, 0, stream>>>(deg_u, deg_i, bsum_u, bsum_i);
    scanB_kernel<<<2, 1024, 0, stream>>>(bsum_u, bpre_u, bsum_i, bpre_i);
    scanC_kernel<<<NB_U + NB_I, 256, 0, stream>>>(deg_u, deg_i, bpre_u, bpre_i, rowptr_u, rowptr_i);
    fill_kernel<<<2048, 256, 0, stream>>>(u_idx, i_idx, w_u2i, w_i2u,
                                          rank_u, rank_i, rowptr_u, rowptr_i,
                                          edges_u, edges_i);

    // ---- layer 0 (u + i in one dispatch) ----
    transform_fused_kernel<<<tu_blocks + ti_blocks, 256, 0, stream>>>(
        user_emb, item_emb, rowptr_u, edges_u, WuT, hu1,
        item_emb, user_emb, rowptr_i, edges_i, WiT, hi1, tu_blocks);

    // ---- layer 1 (u + i in one dispatch) ----
    transform_fused_kernel<<<tu_blocks + ti_blocks, 256, 0, stream>>>(
        hu1, hi1, rowptr_u, edges_u, WuT + 8192, out,
        hi1, hu1, rowptr_i, edges_i, WiT + 8192, out + (size_t)N_USERS * 64, tu_blocks);
}

// Round 6
// 1378.678 us; speedup vs baseline: 3.8958x; 3.8958x over previous
//
#include <hip/hip_runtime.h>

// GraphSAGE-CF on MI355X — round 11.
// Round-10 post-mortem: stateless gather = one LDS atomic PER EDGE (~410M
// lane-RMWs/dispatch); same-address RMW chains serialize at the banks ->
// 2500us with all pipes idle. Register accumulation per row-segment is
// essential (round 5 proved it: flush once per row-change).
// launch_bounds(256,B>4) evidence (r6/7/9): VGPR cap lands ~256/B (half of
// doc'd), spills this kernel; B=4 caps occupancy ~40%. So: NO waves-per-eu
// attribute at all — occupancy from resources: LDS 24576 -> 6 blocks/CU,
// VGPR<=64 -> no wave limit.
// Gather v3: packed-P edges (r10 fill, verified) + 4 sub-chains/wave with
// register gacc + flush-on-P-change (wave-uniform branch, no binary search,
// no rp_s). ~56-60 VGPRs.
//
// ws layout (4-byte words):
//   WuT[2][128][64] @0   WiT @16384          Wt[l][k][j]=W[l][j][k]
//   hu1[200000][64]   hi1[100000][64]
//   edges_u uint2[3.2M]   (col | P<<18, w bits) by user row
//   edges_i uint2[3.2M]   (col | P<<18, w bits) by item row
//   rank_u ushort[3.2M]  rank_i ushort[3.2M]
//   rowptr_u[200001]  rowptr_i[100001]
//   deg_u[200000]  deg_i[100000]
//   bsum_u[782] bpre_u[782] bsum_i[391] bpre_i[391]

#define N_USERS 200000
#define N_ITEMS 100000
#define N_EDGES 3200000
#define NB_U 782      // ceil(200000/256)
#define NB_I 391      // ceil(100000/256)

typedef float v2f __attribute__((ext_vector_type(2)));

// ---------- W convert + transpose:  Wt[l][k][j] = W[l][j][k] ----------
__global__ __launch_bounds__(256) void wprep_kernel(
    const float* __restrict__ Wu, const float* __restrict__ Wi,
    float* __restrict__ WuT, float* __restrict__ WiT)
{
    int idx = blockIdx.x * 256 + threadIdx.x;     // 0..32767
    const float* src = Wu;
    float* dst = WuT;
    int i = idx;
    if (idx >= 16384) { src = Wi; dst = WiT; i = idx - 16384; }
    int l = i >> 13;
    int r = i & 8191;
    int j = r >> 7;           // out col 0..63
    int k = r & 127;          // in  idx 0..127
    dst[l * 8192 + k * 64 + j] = src[i];
}

// ---------- degree histogram + per-edge rank (atomic return is the rank) ----
__global__ __launch_bounds__(256) void hist_kernel(
    const int* __restrict__ u_idx, const int* __restrict__ i_idx,
    int* __restrict__ deg_u, int* __restrict__ deg_i,
    unsigned short* __restrict__ rank_u, unsigned short* __restrict__ rank_i)
{
    int t = blockIdx.x * 256 + threadIdx.x;     // < 2E
    if (t < N_EDGES) {
        rank_u[t] = (unsigned short)atomicAdd(&deg_u[u_idx[t]], 1);
    } else {
        int e = t - N_EDGES;
        rank_i[e] = (unsigned short)atomicAdd(&deg_i[i_idx[e]], 1);
    }
}

// ---------- scan phase A: per-block sums ----------
__global__ __launch_bounds__(256) void scanA_kernel(
    const int* __restrict__ deg_u, const int* __restrict__ deg_i,
    int* __restrict__ bsum_u, int* __restrict__ bsum_i)
{
    int b = blockIdx.x;
    const int* deg; int n; int* bs; int bb;
    if (b < NB_U) { deg = deg_u; n = N_USERS; bs = bsum_u; bb = b; }
    else          { deg = deg_i; n = N_ITEMS; bs = bsum_i; bb = b - NB_U; }
    int i = bb * 256 + threadIdx.x;
    int v = (i < n) ? deg[i] : 0;
    #pragma unroll
    for (int off = 1; off < 64; off <<= 1) v += __shfl_xor(v, off);
    __shared__ int ws4[4];
    int wv = threadIdx.x >> 6;
    if ((threadIdx.x & 63) == 0) ws4[wv] = v;
    __syncthreads();
    if (threadIdx.x == 0) bs[bb] = ws4[0] + ws4[1] + ws4[2] + ws4[3];
}

// ---------- scan phase B: exclusive scan of block sums ----------
__global__ __launch_bounds__(1024) void scanB_kernel(
    const int* __restrict__ bsum_u, int* __restrict__ bpre_u,
    const int* __restrict__ bsum_i, int* __restrict__ bpre_i)
{
    __shared__ int s[1024];
    const int* src; int* dst; int n;
    if (blockIdx.x == 0) { src = bsum_u; dst = bpre_u; n = NB_U; }
    else                 { src = bsum_i; dst = bpre_i; n = NB_I; }
    int t = threadIdx.x;
    int v = (t < n) ? src[t] : 0;
    s[t] = v; __syncthreads();
    #pragma unroll
    for (int off = 1; off < 1024; off <<= 1) {
        int x = (t >= off) ? s[t - off] : 0;
        __syncthreads();
        s[t] += x;
        __syncthreads();
    }
    if (t < n) dst[t] = s[t] - v;   // exclusive
}

// ---------- scan phase C: rowptr = bpre + intra-block exclusive ----------
__global__ __launch_bounds__(256) void scanC_kernel(
    const int* __restrict__ deg_u, const int* __restrict__ deg_i,
    const int* __restrict__ bpre_u, const int* __restrict__ bpre_i,
    int* __restrict__ rowptr_u, int* __restrict__ rowptr_i)
{
    int b = blockIdx.x;
    const int* deg; int n; const int* bpre; int* rowptr; int bb;
    if (b < NB_U) { deg = deg_u; n = N_USERS; bpre = bpre_u; rowptr = rowptr_u; bb = b; }
    else          { deg = deg_i; n = N_ITEMS; bpre = bpre_i; rowptr = rowptr_i; bb = b - NB_U; }
    int t = threadIdx.x;
    int i = bb * 256 + t;
    int d = (i < n) ? deg[i] : 0;
    __shared__ int s[256];
    s[t] = d; __syncthreads();
    #pragma unroll
    for (int off = 1; off < 256; off <<= 1) {
        int x = (t >= off) ? s[t - off] : 0;
        __syncthreads();
        s[t] += x;
        __syncthreads();
    }
    int val = bpre[bb] + (s[t] - d);
    if (i < n) rowptr[i] = val;
    if (b == 0 && t == 0) { rowptr_u[N_USERS] = N_EDGES; rowptr_i[N_ITEMS] = N_EDGES; }
}

// ---------- CSR fill: no atomics; XCD-partitioned by destination row ----------
// Packs dest-row info into edge.x: bits 0..17 = col, bits 18..29 =
// P = (rowlocal<<6) | xsw, where xsw = ((rowlocal>>1)&3)<<3.
// Gather's swizzled LDS word = P ^ lane (lane<64, xsw in low 6 bits of P).
__global__ __launch_bounds__(256) void fill_kernel(
    const int* __restrict__ u_idx, const int* __restrict__ i_idx,
    const float* __restrict__ w_u2i, const float* __restrict__ w_i2u,
    const unsigned short* __restrict__ rank_u, const unsigned short* __restrict__ rank_i,
    const int* __restrict__ rowptr_u, const int* __restrict__ rowptr_i,
    uint2* __restrict__ edges_u, uint2* __restrict__ edges_i)
{
    const int part   = blockIdx.x & 7;
    const int slot   = blockIdx.x >> 3;
    const int nslots = gridDim.x >> 3;
    const int stride = nslots * 256;

    for (int e = slot * 256 + threadIdx.x; e < N_EDGES; e += stride) {
        int ru = u_idx[e];
        int ri = i_idx[e];
        if ((ru & 7) == part) {
            int p = rowptr_u[ru] + rank_u[e];
            unsigned rl = (unsigned)(ru & 63);
            unsigned P  = (rl << 6) | (((rl >> 1) & 3) << 3);
            edges_u[p] = make_uint2((unsigned)ri | (P << 18), __float_as_uint(w_u2i[e]));
        }
        if ((ri & 7) == part) {
            int p = rowptr_i[ri] + rank_i[e];
            unsigned rl = (unsigned)(ri & 63);
            unsigned P  = (rl << 6) | (((rl >> 1) & 3) << 3);
            edges_i[p] = make_uint2((unsigned)ru | (P << 18), __float_as_uint(w_i2u[e]));
        }
    }
}

// Xs column swizzle: word (row<<6) | (col ^ XSW(row)); XSW multiple of 8 so
// GEMM column reads spread over 4 banks (2-way aliased = free) and gather
// flushes stay a per-row lane permutation (conflict-free).
#define XSW(rr) ((((rr) >> 1) & 3) << 3)

// ---------- fused gather + dense transform + relu + l2norm (both sides) ----------
// LDS = Ws[2048] + Xs[4096] floats = 24576 B -> 6 blocks/CU (no waves-per-eu
// attr; occupancy from resources; VGPR target <=64).
// W staged in 8KB quarters (32 k-rows); 4 GEMM sub-phases.
// Gather: 4 contiguous sub-chains per wave, register gacc accumulation,
// ds_add flush only on P-change (wave-uniform branch).
__global__ __launch_bounds__(256) void transform_fused_kernel(
    const float* __restrict__ hself_u, const float* __restrict__ hsrc_u,
    const int* __restrict__ rowptr_u, const uint2* __restrict__ edges_u,
    const float* __restrict__ WtU, float* __restrict__ out_u,
    const float* __restrict__ hself_i, const float* __restrict__ hsrc_i,
    const int* __restrict__ rowptr_i, const uint2* __restrict__ edges_i,
    const float* __restrict__ WtI, float* __restrict__ out_i,
    int nbu)
{
    __shared__ float Ws[32 * 64];    // 8 KB
    __shared__ float Xs[64 * 64];    // 16 KB, XOR-swizzled columns

    const int tid = threadIdx.x;

    // ---- u,u,i interleave: spreads the heavy (2x gather) item blocks ----
    const int nbt = (int)gridDim.x;
    const int nbi = nbt - nbu;
    int bid = (int)blockIdx.x;
    int g = bid / 3, r = bid - 3 * g;
    bool is_u; int bb;
    if (r < 2) {
        int cand = 2 * g + r;
        if (cand < nbu) { is_u = true;  bb = cand; }
        else            { is_u = false; bb = nbi - (nbt - bid); }
    } else {
        int cand = g;
        if (cand < nbi) { is_u = false; bb = cand; }
        else            { is_u = true;  bb = nbu - (nbt - bid); }
    }

    const float* hself; const float* hsrc; const int* rowptr;
    const uint2* edges; const float* Wt; float* out; int N;
    if (is_u) {
        hself = hself_u; hsrc = hsrc_u; rowptr = rowptr_u; edges = edges_u;
        Wt = WtU; out = out_u; N = N_USERS;
    } else {
        hself = hself_i; hsrc = hsrc_i; rowptr = rowptr_i; edges = edges_i;
        Wt = WtI; out = out_i; N = N_ITEMS;
    }
    const int row0 = bb * 64;

    const int tr = tid >> 3;     // 0..31
    const int tc = tid & 7;      // 0..7
    const int r0 = 2 * tr;
    const int xsw = XSW(r0);     // same for rows r0 and r0+1

    v2f acc2[2][4];
    #pragma unroll
    for (int j = 0; j < 2; ++j)
        #pragma unroll
        for (int c = 0; c < 4; ++c) acc2[j][c] = (v2f){0.f, 0.f};

    // ---- stage self tile into swizzled Xs + Ws quarter 0 (k=0..31) ----
    {
        const float4* wsrc = (const float4*)Wt;
        float4* wdst = (float4*)Ws;
        wdst[tid]       = wsrc[tid];
        wdst[tid + 256] = wsrc[tid + 256];
        #pragma unroll
        for (int i = 0; i < 4; ++i) {
            int idx4 = tid + i * 256;          // float4 index 0..1023
            int rr = idx4 >> 4, c4 = idx4 & 15;
            int gr = row0 + rr; if (gr > N - 1) gr = N - 1;
            float4 v = ((const float4*)(hself + (size_t)gr * 64))[c4];
            // (4*c4+j) ^ XSW = 4*(c4 ^ (XSW>>2)) + j  (XSW is a multiple of 8)
            ((float4*)Xs)[(rr << 4) + (c4 ^ (XSW(rr) >> 2))] = v;
        }
    }
    __syncthreads();

    // ---- GEMM A1: self features, dims 0..31 ----
    #pragma unroll 8
    for (int k2 = 0; k2 < 32; ++k2) {
        int kk = k2;
        float a0 = Xs[(r0 << 6) + (kk ^ xsw)];
        float a1 = Xs[((r0 + 1) << 6) + (kk ^ xsw)];
        float4 b0 = *(const float4*)&Ws[k2 * 64 + 8 * tc];
        float4 b1 = *(const float4*)&Ws[k2 * 64 + 8 * tc + 4];
        v2f bv0 = {b0.x, b0.y}, bv1 = {b0.z, b0.w};
        v2f bv2 = {b1.x, b1.y}, bv3 = {b1.z, b1.w};
        v2f a0v = {a0, a0}, a1v = {a1, a1};
        acc2[0][0] += a0v * bv0; acc2[0][1] += a0v * bv1;
        acc2[0][2] += a0v * bv2; acc2[0][3] += a0v * bv3;
        acc2[1][0] += a1v * bv0; acc2[1][1] += a1v * bv1;
        acc2[1][2] += a1v * bv2; acc2[1][3] += a1v * bv3;
    }
    __syncthreads();

    // ---- stage Ws quarter 1 (k=32..63) ----
    {
        const float4* wsrc = (const float4*)(Wt + 2048);
        float4* wdst = (float4*)Ws;
        wdst[tid]       = wsrc[tid];
        wdst[tid + 256] = wsrc[tid + 256];
    }
    __syncthreads();

    // ---- GEMM A2: self features, dims 32..63 ----
    #pragma unroll 8
    for (int k2 = 0; k2 < 32; ++k2) {
        int kk = 32 + k2;
        float a0 = Xs[(r0 << 6) + (kk ^ xsw)];
        float a1 = Xs[((r0 + 1) << 6) + (kk ^ xsw)];
        float4 b0 = *(const float4*)&Ws[k2 * 64 + 8 * tc];
        float4 b1 = *(const float4*)&Ws[k2 * 64 + 8 * tc + 4];
        v2f bv0 = {b0.x, b0.y}, bv1 = {b0.z, b0.w};
        v2f bv2 = {b1.x, b1.y}, bv3 = {b1.z, b1.w};
        v2f a0v = {a0, a0}, a1v = {a1, a1};
        acc2[0][0] += a0v * bv0; acc2[0][1] += a0v * bv1;
        acc2[0][2] += a0v * bv2; acc2[0][3] += a0v * bv3;
        acc2[1][0] += a1v * bv0; acc2[1][1] += a1v * bv1;
        acc2[1][2] += a1v * bv2; acc2[1][3] += a1v * bv3;
    }
    __syncthreads();   // Ws q1 and self Xs dead

    // ---- zero Xs ----
    {
        float4 z = make_float4(0.f, 0.f, 0.f, 0.f);
        #pragma unroll
        for (int i = 0; i < 4; ++i) ((float4*)Xs)[tid + i * 256] = z;
    }
    __syncthreads();

    // ---- gather: 4 sub-chains/wave, register gacc, flush on P-change ----
    {
        const int wv = tid >> 6;
        const int ln = tid & 63;
        const int e0 = rowptr[row0];
        const int e1 = rowptr[min(row0 + 64, N)];
        const int perw = (e1 - e0 + 3) >> 2;
        const int wsb  = e0 + wv * perw;
        const int web  = min(wsb + perw, e1);
        const int clen = (web - wsb + 3) >> 2;      // 4 chains

        int cs[4], ce[4];
        uint2 ec[4];
        float gacc[4];
        unsigned curP[4];
        #pragma unroll
        for (int c = 0; c < 4; ++c) {
            cs[c] = wsb + c * clen;
            ce[c] = min(cs[c] + clen, web);
            ec[c] = edges[min(cs[c], N_EDGES - 1)];
            gacc[c] = 0.f;
        }
        #pragma unroll
        for (int c = 0; c < 4; ++c) curP[c] = (ec[c].x >> 18) & 0xFFFu;

        #pragma unroll 1
        for (int it = 0; it < clen; ++it) {
            float hv[4], w[4];
            unsigned P[4];
            #pragma unroll
            for (int c = 0; c < 4; ++c) {
                bool valid = (cs[c] + it) < ce[c];
                w[c] = valid ? __uint_as_float(ec[c].y) : 0.f;
                P[c] = (ec[c].x >> 18) & 0xFFFu;
                hv[c] = hsrc[(size_t)(ec[c].x & 0x3FFFFu) * 64 + ln];
            }
            #pragma unroll
            for (int c = 0; c < 4; ++c)
                ec[c] = edges[min(cs[c] + it + 1, N_EDGES - 1)];
            #pragma unroll
            for (int c = 0; c < 4; ++c) {
                if (P[c] != curP[c]) {              // wave-uniform branch
                    atomicAdd(&Xs[(int)curP[c] ^ ln], gacc[c]);
                    gacc[c] = 0.f;
                    curP[c] = P[c];
                }
                gacc[c] = fmaf(w[c], hv[c], gacc[c]);
            }
        }
        #pragma unroll
        for (int c = 0; c < 4; ++c)
            atomicAdd(&Xs[(int)curP[c] ^ ln], gacc[c]);   // final flush
    }
    __syncthreads();   // gather done

    // ---- stage Ws quarter 2 (k=64..95) ----
    {
        const float4* wsrc = (const float4*)(Wt + 4096);
        float4* wdst = (float4*)Ws;
        wdst[tid]       = wsrc[tid];
        wdst[tid + 256] = wsrc[tid + 256];
    }
    __syncthreads();

    // ---- GEMM B1: neighbor features, dims 0..31 ----
    #pragma unroll 8
    for (int k2 = 0; k2 < 32; ++k2) {
        int kk = k2;
        float a0 = Xs[(r0 << 6) + (kk ^ xsw)];
        float a1 = Xs[((r0 + 1) << 6) + (kk ^ xsw)];
        float4 b0 = *(const float4*)&Ws[k2 * 64 + 8 * tc];
        float4 b1 = *(const float4*)&Ws[k2 * 64 + 8 * tc + 4];
        v2f bv0 = {b0.x, b0.y}, bv1 = {b0.z, b0.w};
        v2f bv2 = {b1.x, b1.y}, bv3 = {b1.z, b1.w};
        v2f a0v = {a0, a0}, a1v = {a1, a1};
        acc2[0][0] += a0v * bv0; acc2[0][1] += a0v * bv1;
        acc2[0][2] += a0v * bv2; acc2[0][3] += a0v * bv3;
        acc2[1][0] += a1v * bv0; acc2[1][1] += a1v * bv1;
        acc2[1][2] += a1v * bv2; acc2[1][3] += a1v * bv3;
    }
    __syncthreads();

    // ---- stage Ws quarter 3 (k=96..127) ----
    {
        const float4* wsrc = (const float4*)(Wt + 6144);
        float4* wdst = (float4*)Ws;
        wdst[tid]       = wsrc[tid];
        wdst[tid + 256] = wsrc[tid + 256];
    }
    __syncthreads();

    // ---- GEMM B2: neighbor features, dims 32..63 ----
    #pragma unroll 8
    for (int k2 = 0; k2 < 32; ++k2) {
        int kk = 32 + k2;
        float a0 = Xs[(r0 << 6) + (kk ^ xsw)];
        float a1 = Xs[((r0 + 1) << 6) + (kk ^ xsw)];
        float4 b0 = *(const float4*)&Ws[k2 * 64 + 8 * tc];
        float4 b1 = *(const float4*)&Ws[k2 * 64 + 8 * tc + 4];
        v2f bv0 = {b0.x, b0.y}, bv1 = {b0.z, b0.w};
        v2f bv2 = {b1.x, b1.y}, bv3 = {b1.z, b1.w};
        v2f a0v = {a0, a0}, a1v = {a1, a1};
        acc2[0][0] += a0v * bv0; acc2[0][1] += a0v * bv1;
        acc2[0][2] += a0v * bv2; acc2[0][3] += a0v * bv3;
        acc2[1][0] += a1v * bv0; acc2[1][1] += a1v * bv1;
        acc2[1][2] += a1v * bv2; acc2[1][3] += a1v * bv3;
    }

    // ---- epilogue: relu, row L2 norm (8 lanes per row), store ----
    #pragma unroll
    for (int j = 0; j < 2; ++j) {
        float v[8];
        v[0] = fmaxf(acc2[j][0].x, 0.f); v[1] = fmaxf(acc2[j][0].y, 0.f);
        v[2] = fmaxf(acc2[j][1].x, 0.f); v[3] = fmaxf(acc2[j][1].y, 0.f);
        v[4] = fmaxf(acc2[j][2].x, 0.f); v[5] = fmaxf(acc2[j][2].y, 0.f);
        v[6] = fmaxf(acc2[j][3].x, 0.f); v[7] = fmaxf(acc2[j][3].y, 0.f);
        float s = 0.f;
        #pragma unroll
        for (int c = 0; c < 8; ++c) s = fmaf(v[c], v[c], s);
        s += __shfl_xor(s, 1);
        s += __shfl_xor(s, 2);
        s += __shfl_xor(s, 4);
        float nrm = sqrtf(s);
        float inv = 1.f / fmaxf(nrm, 1e-12f);
        int gr = row0 + r0 + j;
        if (gr < N) {
            float4 o0 = make_float4(v[0]*inv, v[1]*inv, v[2]*inv, v[3]*inv);
            float4 o1 = make_float4(v[4]*inv, v[5]*inv, v[6]*inv, v[7]*inv);
            float* p = out + gr * 64 + 8 * tc;
            *(float4*)p       = o0;
            *(float4*)(p + 4) = o1;
        }
    }
}

extern "C" void kernel_launch(void* const* d_in, const int* in_sizes, int n_in,
                              void* d_out, int out_size, void* d_ws, size_t ws_size,
                              hipStream_t stream)
{
    (void)in_sizes; (void)n_in; (void)out_size; (void)ws_size;

    const float* user_emb = (const float*)d_in[0];
    const float* item_emb = (const float*)d_in[1];
    const float* Wu       = (const float*)d_in[2];
    const float* Wi       = (const float*)d_in[3];
    const int*   u_idx    = (const int*)d_in[4];
    const int*   i_idx    = (const int*)d_in[5];
    const float* w_u2i    = (const float*)d_in[6];
    const float* w_i2u    = (const float*)d_in[7];
    float* out = (float*)d_out;

    float* ws      = (float*)d_ws;
    float* WuT     = ws;                            // 16384
    float* WiT     = WuT + 16384;                   // 16384
    float* hu1     = WiT + 16384;                   // 12,800,000
    float* hi1     = hu1 + N_USERS * 64;            // 6,400,000
    uint2* edges_u = (uint2*)(hi1 + N_ITEMS * 64);  // 3.2M uint2
    uint2* edges_i = edges_u + N_EDGES;             // 3.2M uint2
    unsigned short* rank_u = (unsigned short*)(edges_i + N_EDGES);  // 3.2M ushort
    unsigned short* rank_i = rank_u + N_EDGES;                      // 3.2M ushort
    int* rowptr_u = (int*)(rank_i + N_EDGES);       // 200001
    int* rowptr_i = rowptr_u + (N_USERS + 1);       // 100001
    int* deg_u    = rowptr_i + (N_ITEMS + 1);       // 200000
    int* deg_i    = deg_u + N_USERS;                // 100000
    int* bsum_u   = deg_i + N_ITEMS;
    int* bpre_u   = bsum_u + NB_U;
    int* bsum_i   = bpre_u + NB_U;
    int* bpre_i   = bsum_i + NB_I;

    const int tu_blocks = (N_USERS + 63) / 64;        // 3125
    const int ti_blocks = (N_ITEMS + 63) / 64;        // 1563
    const int e2_blocks = (2 * N_EDGES) / 256;        // 25000

    // ---- CSR build (both sides) ----
    wprep_kernel<<<128, 256, 0, stream>>>(Wu, Wi, WuT, WiT);
    hipMemsetAsync(deg_u, 0, (size_t)(N_USERS + N_ITEMS) * 4, stream);
    hist_kernel<<<e2_blocks, 256, 0, stream>>>(u_idx, i_idx, deg_u, deg_i, rank_u, rank_i);
    scanA_kernel<<<NB_U + NB_I, 256, 0, stream>>>(deg_u, deg_i, bsum_u, bsum_i);
    scanB_kernel<<<2, 1024, 0, stream>>>(bsum_u, bpre_u, bsum_i, bpre_i);
    scanC_kernel<<<NB_U + NB_I, 256, 0, stream>>>(deg_u, deg_i, bpre_u, bpre_i, rowptr_u, rowptr_i);
    fill_kernel<<<2048, 256, 0, stream>>>(u_idx, i_idx, w_u2i, w_i2u,
                                          rank_u, rank_i, rowptr_u, rowptr_i,
                                          edges_u, edges_i);

    // ---- layer 0 (u + i in one dispatch) ----
    transform_fused_kernel<<<tu_blocks + ti_blocks, 256, 0, stream>>>(
        user_emb, item_emb, rowptr_u, edges_u, WuT, hu1,
        item_emb, user_emb, rowptr_i, edges_i, WiT, hi1, tu_blocks);

    // ---- layer 1 (u + i in one dispatch) ----
    transform_fused_kernel<<<tu_blocks + ti_blocks, 256, 0, stream>>>(
        hu1, hi1, rowptr_u, edges_u, WuT + 8192, out,
        hi1, hu1, rowptr_i, edges_i, WiT + 8192, out + (size_t)N_USERS * 64, tu_blocks);
}